// Round 8
// baseline (29.929 us; speedup 1.0000x reference)
//
#include <hip/hip_runtime.h>
#include <math.h>

// inputs [B=1024, 7, 7, C=512] f32 NHWC; out [B, 512]:
//   out[b][0:22]          = top-22 of center pixel (3,3)  (k_c = 512%49)
//   out[b][22 + p*10 + j] = top-10 of pixel p             (k_pp = 512//49)
#define NPIX 49
#define C_CH 512
#define CENTER_PIX 24
#define K_PP 10
#define K_C 22
#define CENTER_BLOCKS 1024  // FIRST: long-serial-latency waves start at t=0
#define MAIN_BLOCKS 3136    // 1 wave each x 4 iters x 4 pixels = 50176 pixels
#define ITERS 4

__device__ __forceinline__ float ibc(int x) { return __int_as_float(x); }
__device__ __forceinline__ int fbc(float x) { return __float_as_int(x); }

// Async HBM -> LDS, 16B per lane. LDS dest = uniform base + lane*16 (HW rule,
// m104/m108); global src is per-lane. Zero VGPR cost for prefetch.
#define GLL(gp, lp)                                                          \
    __builtin_amdgcn_global_load_lds(                                        \
        (const __attribute__((address_space(1))) unsigned int*)(gp),         \
        (__attribute__((address_space(3))) unsigned int*)(lp), 16, 0, 0)

// Descending compare-exchange.
__device__ __forceinline__ void ce(float& a, float& b) {
    const float mx = fmaxf(a, b), mn = fminf(a, b);
    a = mx; b = mn;
}

// Sort 8 descending — Batcher odd-even mergesort, 19 CE. (Proven R1-R7.)
__device__ __forceinline__ void sort8_desc(float* v) {
    ce(v[0],v[1]); ce(v[2],v[3]); ce(v[4],v[5]); ce(v[6],v[7]);
    ce(v[0],v[2]); ce(v[1],v[3]); ce(v[4],v[6]); ce(v[5],v[7]);
    ce(v[1],v[2]); ce(v[5],v[6]);
    ce(v[0],v[4]); ce(v[1],v[5]); ce(v[2],v[6]); ce(v[3],v[7]);
    ce(v[2],v[4]); ce(v[3],v[5]);
    ce(v[1],v[2]); ce(v[3],v[4]); ce(v[5],v[6]);
}

// Clean a cyclic-bitonic 10-seq to descending order. (Proven R4-R7.)
__device__ __forceinline__ void bitonic10_clean(float (&c)[10]) {
    ce(c[0],c[8]); ce(c[1],c[9]);
    ce(c[2],c[6]); ce(c[3],c[7]); ce(c[4],c[8]); ce(c[5],c[9]);
    ce(c[2],c[4]); ce(c[3],c[5]); ce(c[6],c[8]); ce(c[7],c[9]);
    ce(c[0],c[1]); ce(c[2],c[3]); ce(c[4],c[5]); ce(c[6],c[7]); ce(c[8],c[9]);
}

// Merge two descending sorted-8 lists -> descending top-10, in place. (R6/R7.)
__device__ __forceinline__ void merge88_top10(float (&a)[8], float (&b)[8],
                                              float (&L)[10]) {
#pragma unroll
    for (int i = 0; i < 8; ++i) {
        const float mx = fmaxf(a[i], b[7 - i]);
        b[7 - i] = fminf(a[i], b[7 - i]);   // l: ranks 9..16 (cyclic bitonic)
        a[i] = mx;                          // h: top-8     (cyclic bitonic)
    }
    ce(a[0],a[4]); ce(a[1],a[5]); ce(a[2],a[6]); ce(a[3],a[7]);
    ce(a[0],a[2]); ce(a[1],a[3]); ce(a[4],a[6]); ce(a[5],a[7]);
    ce(a[0],a[1]); ce(a[2],a[3]); ce(a[4],a[5]); ce(a[6],a[7]);
    const float m0 = fmaxf(b[0], b[4]), m1 = fmaxf(b[1], b[5]);
    const float m2 = fmaxf(b[2], b[6]), m3 = fmaxf(b[3], b[7]);
    const float n0 = fmaxf(m0, m2), n1 = fmaxf(m1, m3);
#pragma unroll
    for (int i = 0; i < 8; ++i) L[i] = a[i];
    L[8] = fmaxf(n0, n1);
    L[9] = fminf(n0, n1);
}

// a = top-10 of (sorted-10 a ∪ sorted-8 b). (Proven R5-R7.)
__device__ __forceinline__ void merge8_into10(float (&a)[10], const float (&b)[8]) {
    float c[10];
    c[0] = a[0]; c[1] = a[1];
#pragma unroll
    for (int i = 2; i < 10; ++i) c[i] = fmaxf(a[i], b[9 - i]);
    bitonic10_clean(c);
#pragma unroll
    for (int i = 0; i < 10; ++i) a[i] = c[i];
}

// Cross-lane tree level: merge own sorted-10 with row-rotated partner's.
template <int CTRL>
__device__ __forceinline__ void tree_level(float (&T)[10]) {
    float c[10];
#pragma unroll
    for (int i = 0; i < 10; ++i) {
        const int s = fbc(T[9 - i]);
        const int p = __builtin_amdgcn_update_dpp(s, s, CTRL, 0xF, 0xF, false);
        c[i] = fmaxf(T[i], ibc(p));
    }
    bitonic10_clean(c);
#pragma unroll
    for (int i = 0; i < 10; ++i) T[i] = c[i];
}

// ---- center-pixel path (R2-proven serial extraction, 1024 waves only) ----
template <int CTRL>
__device__ __forceinline__ float dpp_maxf(float x) {
    const int xi = fbc(x);
    const int yi = __builtin_amdgcn_update_dpp(xi, xi, CTRL, 0xF, 0xF, false);
    return fmaxf(x, ibc(yi));
}

__device__ __forceinline__ float wave_max_uniform(float x) {
    x = dpp_maxf<0x111>(x);  // row_shr:1
    x = dpp_maxf<0x112>(x);  // row_shr:2
    x = dpp_maxf<0x114>(x);  // row_shr:4
    x = dpp_maxf<0x118>(x);  // row_shr:8
    x = dpp_maxf<0x142>(x);  // row_bcast15
    x = dpp_maxf<0x143>(x);  // row_bcast31
    return ibc(__builtin_amdgcn_readlane(fbc(x), 63));
}

__device__ __forceinline__ void round1(float (&v)[8], float& res, int lane, int it) {
    const float m = wave_max_uniform(v[0]);
    const unsigned long long msk = __ballot(v[0] == m);
    const int owner = __ffsll(msk) - 1;
    const bool own = (lane == owner);
    v[0] = own ? v[1] : v[0];
    v[1] = own ? v[2] : v[1];
    v[2] = own ? v[3] : v[2];
    v[3] = own ? v[4] : v[3];
    v[4] = own ? v[5] : v[4];
    v[5] = own ? v[6] : v[5];
    v[6] = own ? v[7] : v[6];
    v[7] = own ? -INFINITY : v[7];
    res = (lane == it) ? m : res;
}

// One wave per block. Wave-private LDS double buffer (2 x 8 KB), no barriers.
// Prefetch next iteration's 8 KB via global_load_lds (no VGPR cost), counted
// s_waitcnt vmcnt(8) keeps the new loads in flight across the compute phase.
__global__ __launch_bounds__(64) void
channel_topk_kernel(const float* __restrict__ in, float* __restrict__ out) {
    __shared__ float sbuf[2][2048];   // 16 KB -> 10 blocks/CU (LDS-limited)
    const int lane = threadIdx.x & 63;

    if (blockIdx.x < CENTER_BLOCKS) {
        // ---- center path: one wave per batch, top-22 of pixel (3,3) ----
        const int c = blockIdx.x;
        const float* srcc = in + ((size_t)c * NPIX + CENTER_PIX) * C_CH;
        const float4 a0 = *reinterpret_cast<const float4*>(srcc + lane * 4);
        const float4 a1 = *reinterpret_cast<const float4*>(srcc + 256 + lane * 4);
        float v[8] = {a0.x, a0.y, a0.z, a0.w, a1.x, a1.y, a1.z, a1.w};
        sort8_desc(v);
        float res = 0.0f;
#pragma unroll
        for (int it = 0; it < K_C; ++it) round1(v, res, lane, it);
        if (lane < K_C) out[(size_t)c * C_CH + lane] = res;
        return;
    }

    // ---- main path: 16 lanes/pixel, 4 pixels/iter, 4 iters/wave ----
    const int wave = blockIdx.x - CENTER_BLOCKS;      // 0..3135
    const int g = lane & 15;
    const int sub = lane >> 4;
    // Lane's global base: pixel (wave*16 + sub), channels g*4 + j*64 + {0..3}.
    // Iteration stride: 4 pixels = 2048 floats.
    const float* gbase = in + ((size_t)wave * 16 + sub) * C_CH + g * 4;

    // Prologue: stage iteration 0 into buffer 0.
#pragma unroll
    for (int j = 0; j < 8; ++j) GLL(gbase + j * 64, &sbuf[0][j * 256]);

#pragma unroll
    for (int i = 0; i < ITERS; ++i) {
        const float* cur = &sbuf[i & 1][lane * 4];

        // Issue next iteration's 8 staging loads into the other buffer, then
        // wait only for the CURRENT buffer (8 newest ops stay outstanding).
        if (i + 1 < ITERS) {
            const float* gnext = gbase + (size_t)(i + 1) * 4 * C_CH;
#pragma unroll
            for (int j = 0; j < 8; ++j)
                GLL(gnext + j * 64, &sbuf[(i + 1) & 1][j * 256]);
            asm volatile("s_waitcnt vmcnt(8)" ::: "memory");
        } else {
            asm volatile("s_waitcnt vmcnt(0)" ::: "memory");
        }

        // LDS -> regs: 8 x ds_read_b128, conflict-free linear layout.
        const float4 t0 = *reinterpret_cast<const float4*>(cur);
        const float4 t1 = *reinterpret_cast<const float4*>(cur + 256);
        const float4 t2 = *reinterpret_cast<const float4*>(cur + 512);
        const float4 t3 = *reinterpret_cast<const float4*>(cur + 768);
        const float4 t4 = *reinterpret_cast<const float4*>(cur + 1024);
        const float4 t5 = *reinterpret_cast<const float4*>(cur + 1280);
        const float4 t6 = *reinterpret_cast<const float4*>(cur + 1536);
        const float4 t7 = *reinterpret_cast<const float4*>(cur + 1792);

        float a[8] = {t0.x, t0.y, t0.z, t0.w, t1.x, t1.y, t1.z, t1.w};
        float b[8] = {t2.x, t2.y, t2.z, t2.w, t3.x, t3.y, t3.z, t3.w};
        sort8_desc(a);
        sort8_desc(b);
        float L[10];
        merge88_top10(a, b, L);               // in place: a,b clobbered

        float s1[8] = {t4.x, t4.y, t4.z, t4.w, t5.x, t5.y, t5.z, t5.w};
        sort8_desc(s1);
        merge8_into10(L, s1);
        float s2[8] = {t6.x, t6.y, t6.z, t6.w, t7.x, t7.y, t7.z, t7.w};
        sort8_desc(s2);
        merge8_into10(L, s2);                 // L = lane's top-10 of 32 ch

        // rotate-merge across the 16-lane row: exact binary coverage.
        tree_level<0x121>(L);  // row_ror:1
        tree_level<0x122>(L);  // row_ror:2
        tree_level<0x124>(L);  // row_ror:4
        tree_level<0x128>(L);  // row_ror:8

        const int pix = wave * 16 + i * 4 + sub;
        const int bb = pix / NPIX;
        const int p = pix - bb * NPIX;
        float r = L[0];
#pragma unroll
        for (int k = 1; k < 10; ++k) r = (g == k) ? L[k] : r;
        if (g < K_PP) out[(size_t)bb * C_CH + K_C + p * K_PP + g] = r;
    }
}

extern "C" void kernel_launch(void* const* d_in, const int* in_sizes, int n_in,
                              void* d_out, int out_size, void* d_ws, size_t ws_size,
                              hipStream_t stream) {
    const float* in = (const float*)d_in[0];
    float* out = (float*)d_out;
    channel_topk_kernel<<<CENTER_BLOCKS + MAIN_BLOCKS, 64, 0, stream>>>(in, out);
}

// Round 10
// 24.308 us; speedup vs baseline: 1.2312x; 1.2312x over previous
//
#include <hip/hip_runtime.h>
#include <math.h>

// inputs [B=1024, 7, 7, C=512] f32 NHWC; out [B, 512]:
//   out[b][0:22]          = top-22 of center pixel (3,3)  (k_c = 512%49)
//   out[b][22 + p*10 + j] = top-10 of pixel p             (k_pp = 512//49)
#define NPIX 49
#define C_CH 512
#define CENTER_PIX 24
#define K_PP 10
#define K_C 22
#define CENTER_BLOCKS 256   // FIRST: long-serial-latency waves start at t=0
#define MAIN_BLOCKS 1568    // x4 waves x8 pixels = 50176 pixels

__device__ __forceinline__ float ibc(int x) { return __int_as_float(x); }
__device__ __forceinline__ int fbc(float x) { return __float_as_int(x); }

// Descending compare-exchange.
__device__ __forceinline__ void ce(float& a, float& b) {
    const float mx = fmaxf(a, b), mn = fminf(a, b);
    a = mx; b = mn;
}

// Sort 8 descending — Batcher odd-even mergesort, 19 CE. (Proven R1-R8.)
__device__ __forceinline__ void sort8_desc(float* v) {
    ce(v[0],v[1]); ce(v[2],v[3]); ce(v[4],v[5]); ce(v[6],v[7]);
    ce(v[0],v[2]); ce(v[1],v[3]); ce(v[4],v[6]); ce(v[5],v[7]);
    ce(v[1],v[2]); ce(v[5],v[6]);
    ce(v[0],v[4]); ce(v[1],v[5]); ce(v[2],v[6]); ce(v[3],v[7]);
    ce(v[2],v[4]); ce(v[3],v[5]);
    ce(v[1],v[2]); ce(v[3],v[4]); ce(v[5],v[6]);
}

// Clean a cyclic-bitonic 10-seq to descending order. (Proven R4-R8.)
__device__ __forceinline__ void bitonic10_clean(float (&c)[10]) {
    ce(c[0],c[8]); ce(c[1],c[9]);
    ce(c[2],c[6]); ce(c[3],c[7]); ce(c[4],c[8]); ce(c[5],c[9]);
    ce(c[2],c[4]); ce(c[3],c[5]); ce(c[6],c[8]); ce(c[7],c[9]);
    ce(c[0],c[1]); ce(c[2],c[3]); ce(c[4],c[5]); ce(c[6],c[7]); ce(c[8],c[9]);
}

// Merge two descending sorted-8 lists -> descending top-10, in place. (R6-R8.)
__device__ __forceinline__ void merge88_top10(float (&a)[8], float (&b)[8],
                                              float (&L)[10]) {
#pragma unroll
    for (int i = 0; i < 8; ++i) {
        const float mx = fmaxf(a[i], b[7 - i]);
        b[7 - i] = fminf(a[i], b[7 - i]);   // l: ranks 9..16 (cyclic bitonic)
        a[i] = mx;                          // h: top-8     (cyclic bitonic)
    }
    ce(a[0],a[4]); ce(a[1],a[5]); ce(a[2],a[6]); ce(a[3],a[7]);
    ce(a[0],a[2]); ce(a[1],a[3]); ce(a[4],a[6]); ce(a[5],a[7]);
    ce(a[0],a[1]); ce(a[2],a[3]); ce(a[4],a[5]); ce(a[6],a[7]);
    const float m0 = fmaxf(b[0], b[4]), m1 = fmaxf(b[1], b[5]);
    const float m2 = fmaxf(b[2], b[6]), m3 = fmaxf(b[3], b[7]);
    const float n0 = fmaxf(m0, m2), n1 = fmaxf(m1, m3);
#pragma unroll
    for (int i = 0; i < 8; ++i) L[i] = a[i];
    L[8] = fmaxf(n0, n1);
    L[9] = fminf(n0, n1);
}

// a = top-10 of (sorted-10 a ∪ sorted-8 b). (Proven R5-R8.)
__device__ __forceinline__ void merge8_into10(float (&a)[10], const float (&b)[8]) {
    float c[10];
    c[0] = a[0]; c[1] = a[1];
#pragma unroll
    for (int i = 2; i < 10; ++i) c[i] = fmaxf(a[i], b[9 - i]);
    bitonic10_clean(c);
#pragma unroll
    for (int i = 0; i < 10; ++i) a[i] = c[i];
}

// Cross-lane tree level: merge own sorted-10 with DPP partner's.
// CTRL choices below form a 3-round gossip over each 8-lane group:
//   0xB1 = quad_perm [1,0,3,2]  (xor 1)
//   0x4E = quad_perm [2,3,0,1]  (xor 2)
//   0x141 = row_half_mirror     (i <-> 7-i within each 8-lane half-row)
// Coverage per lane: {i} u {i^1} u {i^2,i^3} u {opposite 4-block} = all 8.
template <int CTRL>
__device__ __forceinline__ void tree_level(float (&T)[10]) {
    float c[10];
#pragma unroll
    for (int i = 0; i < 10; ++i) {
        const int s = fbc(T[9 - i]);
        const int p = __builtin_amdgcn_update_dpp(s, s, CTRL, 0xF, 0xF, false);
        c[i] = fmaxf(T[i], ibc(p));
    }
    bitonic10_clean(c);
#pragma unroll
    for (int i = 0; i < 10; ++i) T[i] = c[i];
}

// ---- center-pixel path (R2-proven serial extraction, 1024 waves only) ----
template <int CTRL>
__device__ __forceinline__ float dpp_maxf(float x) {
    const int xi = fbc(x);
    const int yi = __builtin_amdgcn_update_dpp(xi, xi, CTRL, 0xF, 0xF, false);
    return fmaxf(x, ibc(yi));
}

__device__ __forceinline__ float wave_max_uniform(float x) {
    x = dpp_maxf<0x111>(x);  // row_shr:1
    x = dpp_maxf<0x112>(x);  // row_shr:2
    x = dpp_maxf<0x114>(x);  // row_shr:4
    x = dpp_maxf<0x118>(x);  // row_shr:8
    x = dpp_maxf<0x142>(x);  // row_bcast15
    x = dpp_maxf<0x143>(x);  // row_bcast31
    return ibc(__builtin_amdgcn_readlane(fbc(x), 63));
}

__device__ __forceinline__ void round1(float (&v)[8], float& res, int lane, int it) {
    const float m = wave_max_uniform(v[0]);
    const unsigned long long msk = __ballot(v[0] == m);
    const int owner = __ffsll(msk) - 1;
    const bool own = (lane == owner);
    v[0] = own ? v[1] : v[0];
    v[1] = own ? v[2] : v[1];
    v[2] = own ? v[3] : v[2];
    v[3] = own ? v[4] : v[3];
    v[4] = own ? v[5] : v[4];
    v[5] = own ? v[6] : v[5];
    v[6] = own ? v[7] : v[6];
    v[7] = own ? -INFINITY : v[7];
    res = (lane == it) ? m : res;
}

#define LD(j) (*reinterpret_cast<const float4*>(src + (j) * 32))
// NOTE: macro params must not collide with float4 member names (R9 lesson:
// `x.x` substituted BOTH tokens -> t0.t0).
#define PACK8(d, p, q) \
    float d[8] = {(p).x, (p).y, (p).z, (p).w, (q).x, (q).y, (q).z, (q).w}

// 8 lanes per pixel, 64 channels per lane, 8 pixels per wave.
// VGPR cap 128 (no spill); loads interleaved between merge stages so up to
// 8 float4 loads stay outstanding during compute (per-wave MLP).
__global__ __launch_bounds__(256, 4) void
channel_topk_kernel(const float* __restrict__ in, float* __restrict__ out) {
    const int wid = threadIdx.x >> 6;
    const int lane = threadIdx.x & 63;

    if (blockIdx.x < CENTER_BLOCKS) {
        // ---- center path: one wave per batch, top-22 of pixel (3,3) ----
        const int c = blockIdx.x * 4 + wid;  // batch 0..1023
        const float* srcc = in + ((size_t)c * NPIX + CENTER_PIX) * C_CH;
        const float4 a0 = *reinterpret_cast<const float4*>(srcc + lane * 4);
        const float4 a1 = *reinterpret_cast<const float4*>(srcc + 256 + lane * 4);
        float v[8] = {a0.x, a0.y, a0.z, a0.w, a1.x, a1.y, a1.z, a1.w};
        sort8_desc(v);
        float res = 0.0f;
#pragma unroll
        for (int it = 0; it < K_C; ++it) round1(v, res, lane, it);
        if (lane < K_C) out[(size_t)c * C_CH + lane] = res;
        return;
    }

    // ---- main path ----
    const int wave = (blockIdx.x - CENTER_BLOCKS) * 4 + wid;  // 0..6271
    const int g = lane & 7;          // lane within pixel group
    const int sub = lane >> 3;       // pixel subgroup 0..7
    const int pix = wave * 8 + sub;
    // Lane reads channels g*4 + j*32 + {0..3}, j = 0..15. Each 8-lane group
    // covers a contiguous 128 B line per j -> fully coalesced.
    const float* src = in + (size_t)pix * C_CH + g * 4;

    // Batches 0..3 (t0..t7) up front.
    const float4 t0 = LD(0), t1 = LD(1), t2 = LD(2), t3 = LD(3);
    const float4 t4 = LD(4), t5 = LD(5), t6 = LD(6), t7 = LD(7);

    PACK8(a, t0, t1);
    PACK8(b, t2, t3);
    sort8_desc(a);
    sort8_desc(b);
    float L[10];
    merge88_top10(a, b, L);

    // Batches 4,5 issued; batches 2,3 consumed.
    const float4 t8 = LD(8), t9 = LD(9), t10 = LD(10), t11 = LD(11);
    PACK8(s0, t4, t5);
    sort8_desc(s0);
    merge8_into10(L, s0);
    PACK8(s1, t6, t7);
    sort8_desc(s1);
    merge8_into10(L, s1);

    // Batches 6,7 issued; batches 4,5 consumed.
    const float4 t12 = LD(12), t13 = LD(13), t14 = LD(14), t15 = LD(15);
    PACK8(s2, t8, t9);
    sort8_desc(s2);
    merge8_into10(L, s2);
    PACK8(s3, t10, t11);
    sort8_desc(s3);
    merge8_into10(L, s3);
    PACK8(s4, t12, t13);
    sort8_desc(s4);
    merge8_into10(L, s4);
    PACK8(s5, t14, t15);
    sort8_desc(s5);
    merge8_into10(L, s5);      // L = lane's sorted top-10 of its 64 channels

    // 3-level gossip across the 8-lane group -> every lane has pixel top-10.
    tree_level<0xB1>(L);       // quad_perm xor 1
    tree_level<0x4E>(L);       // quad_perm xor 2
    tree_level<0x141>(L);      // row_half_mirror (crosses the 4-blocks)

    const int bb = pix / NPIX;
    const int p = pix - bb * NPIX;
    float* ob = out + (size_t)bb * C_CH + K_C + p * K_PP;
    float r = L[0];
#pragma unroll
    for (int k = 1; k < 8; ++k) r = (g == k) ? L[k] : r;
    ob[g] = r;                               // ranks 0..7 (all 8 lanes)
    const float r2 = (g == 0) ? L[8] : L[9];
    if (g < 2) ob[8 + g] = r2;               // ranks 8,9
}

extern "C" void kernel_launch(void* const* d_in, const int* in_sizes, int n_in,
                              void* d_out, int out_size, void* d_ws, size_t ws_size,
                              hipStream_t stream) {
    const float* in = (const float*)d_in[0];
    float* out = (float*)d_out;
    channel_topk_kernel<<<CENTER_BLOCKS + MAIN_BLOCKS, 256, 0, stream>>>(in, out);
}